// Round 3
// baseline (232.743 us; speedup 1.0000x reference)
//
#include <hip/hip_runtime.h>

// Problem constants (from reference setup_inputs)
constexpr int Bsz   = 1024;     // batch
constexpr int F0    = 20000;    // input features
constexpr int NOUT0 = 5000, NOUT1 = 1000, NOUT2 = 256;
constexpr int NE0   = 100000, NE1 = 50000, NE2 = 10000;
constexpr int CNT_N  = NOUT0 + NOUT1 + NOUT2;   // 6256
constexpr int OFFS_N = CNT_N + 3;               // 6259
constexpr int CSR_N  = NE0 + NE1 + NE2;         // 160000
constexpr int NT     = 1024;    // threads in fused kernel

// ---------------------------------------------------------------------------
// CSR build: count, scan, scatter-pack ((dst<<15)|src, sorted by dst)
__global__ __launch_bounds__(256) void count_edges(
    const int* __restrict__ dst0, const int* __restrict__ dst1,
    const int* __restrict__ dst2, int* __restrict__ cnt)
{
    const int i = blockIdx.x * 256 + threadIdx.x;
    if (i < NE0)                 atomicAdd(&cnt[dst0[i]], 1);
    else if (i < NE0 + NE1)      atomicAdd(&cnt[NOUT0 + dst1[i - NE0]], 1);
    else if (i < NE0 + NE1 + NE2) atomicAdd(&cnt[NOUT0 + NOUT1 + dst2[i - NE0 - NE1]], 1);
}

__global__ __launch_bounds__(1024) void scan_offs(
    const int* __restrict__ cnt, int* __restrict__ offs, int* __restrict__ cursor)
{
    const int L = blockIdx.x;
    const int nout  = (L == 0) ? NOUT0 : (L == 1) ? NOUT1 : NOUT2;
    const int cbase = (L == 0) ? 0 : (L == 1) ? NOUT0 : NOUT0 + NOUT1;
    const int obase = (L == 0) ? 0 : (L == 1) ? NOUT0 + 1 : NOUT0 + NOUT1 + 2;
    const int* c  = cnt + cbase;
    int* ofs      = offs + obase;
    int* cur      = cursor + cbase;

    __shared__ int lds[1024];
    const int t = threadIdx.x;
    constexpr int CHUNK = 5;              // covers nout <= 5120
    const int base = t * CHUNK;
    int vals[CHUNK];
    int local = 0;
#pragma unroll
    for (int k = 0; k < CHUNK; ++k) {
        const int i = base + k;
        const int v = (i < nout) ? c[i] : 0;
        vals[k] = v;
        local += v;
    }
    lds[t] = local;
    __syncthreads();
    for (int d = 1; d < 1024; d <<= 1) {
        const int v = (t >= d) ? lds[t - d] : 0;
        __syncthreads();
        lds[t] += v;
        __syncthreads();
    }
    int excl = lds[t] - local;
#pragma unroll
    for (int k = 0; k < CHUNK; ++k) {
        const int i = base + k;
        if (i < nout) { ofs[i] = excl; cur[i] = excl; }
        excl += vals[k];
    }
    if (t == 1023) ofs[nout] = lds[1023];
}

__global__ __launch_bounds__(256) void scatter_pack(
    const int* __restrict__ src0, const int* __restrict__ dst0,
    const int* __restrict__ src1, const int* __restrict__ dst1,
    const int* __restrict__ src2, const int* __restrict__ dst2,
    int* __restrict__ cursor, unsigned int* __restrict__ pack)
{
    const int i = blockIdx.x * 256 + threadIdx.x;
    if (i < NE0) {
        const int d = dst0[i];
        const int pos = atomicAdd(&cursor[d], 1);
        pack[pos] = (unsigned)src0[i] | ((unsigned)d << 15);
    } else if (i < NE0 + NE1) {
        const int k = i - NE0;
        const int d = dst1[k];
        const int pos = atomicAdd(&cursor[NOUT0 + d], 1);
        pack[NE0 + pos] = (unsigned)src1[k] | ((unsigned)d << 15);
    } else if (i < NE0 + NE1 + NE2) {
        const int k = i - NE0 - NE1;
        const int d = dst2[k];
        const int pos = atomicAdd(&cursor[NOUT0 + NOUT1 + d], 1);
        pack[NE0 + NE1 + pos] = (unsigned)src2[k] | ((unsigned)d << 15);
    }
}

// g[j] = (1/max(cnt,1)) * pnext[j]  (pnext fused; 1.0 for last layer)
__global__ __launch_bounds__(256) void make_g(
    const int* __restrict__ cnt, const float* __restrict__ p1,
    const float* __restrict__ p2, float* __restrict__ g)
{
    const int j = blockIdx.x * 256 + threadIdx.x;
    if (j >= CNT_N) return;
    const float inv = 1.0f / fmaxf((float)cnt[j], 1.0f);
    float pn = 1.0f;
    if (j < NOUT0) pn = p1[j];
    else if (j < NOUT0 + NOUT1) pn = p2[j - NOUT0];
    g[j] = inv * pn;
}

// ---------------------------------------------------------------------------
// Fused per-batch-row network: one block = one batch row, all state in LDS.
__device__ __forceinline__ void walk_layer(
    int t, const unsigned int* __restrict__ pk, int ne, int chunk,
    const float* __restrict__ xin, float* __restrict__ yout)
{
    const int e0 = t * chunk;
    const int e1 = (e0 + chunk < ne) ? e0 + chunk : ne;
    if (e0 >= e1) return;
    float run = 0.f;
    int cur = -1;
    int e = e0;
    for (; e + 4 <= e1; e += 4) {
        const uint4 q = *(const uint4*)(pk + e);
        const unsigned ws[4] = {q.x, q.y, q.z, q.w};
#pragma unroll
        for (int u = 0; u < 4; ++u) {
            const unsigned w = ws[u];
            const int d = (int)(w >> 15);
            const float v = xin[w & 0x7FFFu];
            if (d != cur) {
                if (cur >= 0) atomicAdd(&yout[cur], run);
                cur = d; run = 0.f;
            }
            run += v;
        }
    }
    for (; e < e1; ++e) {
        const unsigned w = pk[e];
        const int d = (int)(w >> 15);
        const float v = xin[w & 0x7FFFu];
        if (d != cur) {
            if (cur >= 0) atomicAdd(&yout[cur], run);
            cur = d; run = 0.f;
        }
        run += v;
    }
    if (cur >= 0) atomicAdd(&yout[cur], run);
}

__global__ __launch_bounds__(NT, 1) void fused_gnn(
    const float* __restrict__ data, const float* __restrict__ p0,
    const unsigned int* __restrict__ pack, const float* __restrict__ g,
    const float* __restrict__ W, const float* __restrict__ bias,
    float* __restrict__ out)
{
    __shared__ float x0s[F0];      // 80000 B
    __shared__ float y0s[NOUT0];   // 20000 B
    __shared__ float y1s[NOUT1];   //  4000 B
    __shared__ float y2s[NOUT2];   //  1024 B

    const int b = blockIdx.x;
    const int t = threadIdx.x;

    // Phase A: x0 = data[b] * p0 (vectorized), zero accumulators
    {
        const float4* __restrict__ dr = (const float4*)(data + (size_t)b * F0);
        const float4* __restrict__ pr = (const float4*)p0;
        float4* xr = (float4*)x0s;
        for (int i = t; i < F0 / 4; i += NT) {
            const float4 d = dr[i];
            const float4 p = pr[i];
            xr[i] = make_float4(d.x * p.x, d.y * p.y, d.z * p.z, d.w * p.w);
        }
    }
    for (int i = t; i < NOUT0; i += NT) y0s[i] = 0.f;
    if (t < NOUT1) y1s[t] = 0.f;
    if (t < NOUT2) y2s[t] = 0.f;
    __syncthreads();

    // Layer 0: 1000 threads x 100 edges
    walk_layer(t, pack, NE0, 100, x0s, y0s);
    __syncthreads();
    for (int j = t; j < NOUT0; j += NT) y0s[j] = fmaxf(y0s[j], 0.f) * g[j];
    __syncthreads();

    // Layer 1: 962 threads x 52 edges
    walk_layer(t, pack + NE0, NE1, 52, y0s, y1s);
    __syncthreads();
    if (t < NOUT1) y1s[t] = fmaxf(y1s[t], 0.f) * g[NOUT0 + t];
    __syncthreads();

    // Layer 2: 834 threads x 12 edges
    walk_layer(t, pack + NE0 + NE1, NE2, 12, y1s, y2s);
    __syncthreads();
    if (t < NOUT2) y2s[t] = fmaxf(y2s[t], 0.f) * g[NOUT0 + NOUT1 + t];
    __syncthreads();

    // Head: wave o (o<10) computes out[b][o] = dot(y2, W[o]) + bias[o]
    const int wid = t >> 6, lane = t & 63;
    if (wid < 10) {
        const float4 w4 = ((const float4*)(W + wid * 256))[lane];
        const float4 v4 = ((const float4*)y2s)[lane];
        float s = w4.x * v4.x + w4.y * v4.y + w4.z * v4.z + w4.w * v4.w;
#pragma unroll
        for (int off = 32; off > 0; off >>= 1) s += __shfl_xor(s, off);
        if (lane == 0) out[(size_t)b * 10 + wid] = s + bias[wid];
    }
}

// ---------------------------------------------------------------------------
extern "C" void kernel_launch(void* const* d_in, const int* in_sizes, int n_in,
                              void* d_out, int out_size, void* d_ws, size_t ws_size,
                              hipStream_t stream)
{
    const float* data = (const float*)d_in[0];
    const float* p0   = (const float*)d_in[1];
    const float* p1   = (const float*)d_in[2];
    const float* p2   = (const float*)d_in[3];
    const float* W    = (const float*)d_in[4];
    const float* bias = (const float*)d_in[5];
    const int* src0 = (const int*)d_in[6];
    const int* dst0 = (const int*)d_in[7];
    const int* src1 = (const int*)d_in[8];
    const int* dst1 = (const int*)d_in[9];
    const int* src2 = (const int*)d_in[10];
    const int* dst2 = (const int*)d_in[11];

    char* ws = (char*)d_ws;
    auto align = [](size_t x) { return (x + 255) & ~size_t(255); };
    size_t o = 0;
    int* cnt    = (int*)(ws + o);          o = align(o + (size_t)CNT_N * 4);
    int* offs   = (int*)(ws + o);          o = align(o + (size_t)OFFS_N * 4);
    int* cursor = (int*)(ws + o);          o = align(o + (size_t)CNT_N * 4);
    unsigned int* pack = (unsigned int*)(ws + o); o = align(o + (size_t)CSR_N * 4);
    float* g    = (float*)(ws + o);        o = align(o + (size_t)CNT_N * 4);

    hipMemsetAsync(cnt, 0, (size_t)CNT_N * 4, stream);

    constexpr int totE = NE0 + NE1 + NE2;
    count_edges<<<(totE + 255) / 256, 256, 0, stream>>>(dst0, dst1, dst2, cnt);
    scan_offs<<<3, 1024, 0, stream>>>(cnt, offs, cursor);
    scatter_pack<<<(totE + 255) / 256, 256, 0, stream>>>(
        src0, dst0, src1, dst1, src2, dst2, cursor, pack);
    make_g<<<(CNT_N + 255) / 256, 256, 0, stream>>>(cnt, p1, p2, g);

    fused_gnn<<<Bsz, NT, 0, stream>>>(data, p0, pack, g, W, bias, (float*)d_out);
}

// Round 4
// 186.683 us; speedup vs baseline: 1.2467x; 1.2467x over previous
//
#include <hip/hip_runtime.h>

// Problem constants (from reference setup_inputs)
constexpr int Bsz   = 1024;     // batch
constexpr int F0    = 20000;    // input features
constexpr int NOUT0 = 5000, NOUT1 = 1000, NOUT2 = 256;
constexpr int NE0   = 100000, NE1 = 50000, NE2 = 10000;
constexpr int CNT_N  = NOUT0 + NOUT1 + NOUT2;   // 6256
constexpr int OFFS_N = CNT_N + 3;               // 6259
constexpr int CSR_N  = NE0 + NE1 + NE2;         // 160000

// ---------------------------------------------------------------------------
// Transpose data (B, F0) -> dataT (F0, B), fused with *p0 row scale.
// 64x64 tile, float4 on both global sides (16B/lane). F-edge guarded.
__global__ __launch_bounds__(256) void transpose_scale(
    const float* __restrict__ data, const float* __restrict__ p0,
    float* __restrict__ dataT)
{
    __shared__ float tile[64][65];
    const int t  = threadIdx.x;
    const int c0 = blockIdx.x * 64;   // F0 dim
    const int r0 = blockIdx.y * 64;   // B dim

    const int f4 = t & 15;            // float4 column group within tile
    const int rr = t >> 4;            // 0..15
    const int col = c0 + f4 * 4;
    if (col < F0) {                   // F0 % 4 == 0, so f4-granular guard is exact
#pragma unroll
        for (int p = 0; p < 4; ++p) {
            const int br = rr + p * 16;
            const float4 v = *(const float4*)&data[(size_t)(r0 + br) * F0 + col];
            tile[br][f4 * 4 + 0] = v.x;
            tile[br][f4 * 4 + 1] = v.y;
            tile[br][f4 * 4 + 2] = v.z;
            tile[br][f4 * 4 + 3] = v.w;
        }
    }
    __syncthreads();

    const int b4 = t & 15;            // float4 group in B dim
    const int fr = t >> 4;            // 0..15
#pragma unroll
    for (int p = 0; p < 4; ++p) {
        const int f = c0 + fr + p * 16;
        if (f < F0) {
            const float s = p0[f];
            float4 v;
            v.x = tile[b4 * 4 + 0][fr + p * 16] * s;
            v.y = tile[b4 * 4 + 1][fr + p * 16] * s;
            v.z = tile[b4 * 4 + 2][fr + p * 16] * s;
            v.w = tile[b4 * 4 + 3][fr + p * 16] * s;
            *(float4*)&dataT[(size_t)f * Bsz + r0 + b4 * 4] = v;
        }
    }
}

// ---------------------------------------------------------------------------
// CSR build: count, scan, scatter (all 3 layers at once)
__global__ __launch_bounds__(256) void count_edges(
    const int* __restrict__ dst0, const int* __restrict__ dst1,
    const int* __restrict__ dst2, int* __restrict__ cnt)
{
    const int i = blockIdx.x * 256 + threadIdx.x;
    if (i < NE0)                 atomicAdd(&cnt[dst0[i]], 1);
    else if (i < NE0 + NE1)      atomicAdd(&cnt[NOUT0 + dst1[i - NE0]], 1);
    else if (i < NE0 + NE1 + NE2) atomicAdd(&cnt[NOUT0 + NOUT1 + dst2[i - NE0 - NE1]], 1);
}

__global__ __launch_bounds__(1024) void scan_offs(
    const int* __restrict__ cnt, int* __restrict__ offs, int* __restrict__ cursor)
{
    const int L = blockIdx.x;
    const int nout  = (L == 0) ? NOUT0 : (L == 1) ? NOUT1 : NOUT2;
    const int cbase = (L == 0) ? 0 : (L == 1) ? NOUT0 : NOUT0 + NOUT1;
    const int obase = (L == 0) ? 0 : (L == 1) ? NOUT0 + 1 : NOUT0 + NOUT1 + 2;
    const int* c  = cnt + cbase;
    int* ofs      = offs + obase;
    int* cur      = cursor + cbase;

    __shared__ int lds[1024];
    const int t = threadIdx.x;
    constexpr int CHUNK = 5;              // covers nout <= 5120
    const int base = t * CHUNK;
    int vals[CHUNK];
    int local = 0;
#pragma unroll
    for (int k = 0; k < CHUNK; ++k) {
        const int i = base + k;
        const int v = (i < nout) ? c[i] : 0;
        vals[k] = v;
        local += v;
    }
    lds[t] = local;
    __syncthreads();
    for (int d = 1; d < 1024; d <<= 1) {
        const int v = (t >= d) ? lds[t - d] : 0;
        __syncthreads();
        lds[t] += v;
        __syncthreads();
    }
    int excl = lds[t] - local;
#pragma unroll
    for (int k = 0; k < CHUNK; ++k) {
        const int i = base + k;
        if (i < nout) { ofs[i] = excl; cur[i] = excl; }
        excl += vals[k];
    }
    if (t == 1023) ofs[nout] = lds[1023];
}

__global__ __launch_bounds__(256) void scatter_edges(
    const int* __restrict__ src0, const int* __restrict__ dst0,
    const int* __restrict__ src1, const int* __restrict__ dst1,
    const int* __restrict__ src2, const int* __restrict__ dst2,
    int* __restrict__ cursor, int* __restrict__ csr)
{
    const int i = blockIdx.x * 256 + threadIdx.x;
    if (i < NE0) {
        const int pos = atomicAdd(&cursor[dst0[i]], 1);
        csr[pos] = src0[i];
    } else if (i < NE0 + NE1) {
        const int k = i - NE0;
        const int pos = atomicAdd(&cursor[NOUT0 + dst1[k]], 1);
        csr[NE0 + pos] = src1[k];
    } else if (i < NE0 + NE1 + NE2) {
        const int k = i - NE0 - NE1;
        const int pos = atomicAdd(&cursor[NOUT0 + NOUT1 + dst2[k]], 1);
        csr[NE0 + NE1 + pos] = src2[k];
    }
}

// ---------------------------------------------------------------------------
// One layer: block j sums rows xT[csr[e]] over its bucket, mean+relu, scaled
// by pnext (the NEXT layer's p, fused), written transposed.
// Edge indices preloaded into LDS (broadcast reads, conflict-free);
// 4-edge unroll with 4 accumulators keeps 4 float4 loads in flight/thread.
constexpr int MAXIDX = 512;   // max edges per dst we preload (Poisson max ~90)

__global__ __launch_bounds__(256) void layer_fwd(
    const float4* __restrict__ xT, const int* __restrict__ csr,
    const int* __restrict__ offs, const float* __restrict__ pnext,
    float4* __restrict__ yT)
{
    __shared__ int sidx[MAXIDX];
    const int j = blockIdx.x;
    const int t = threadIdx.x;
    const int beg = offs[j], end = offs[j + 1];
    const int n = end - beg;
    const int np = n < MAXIDX ? n : MAXIDX;
    for (int i = t; i < np; i += 256) sidx[i] = csr[beg + i];
    __syncthreads();

    float4 a0 = make_float4(0.f, 0.f, 0.f, 0.f);
    float4 a1 = make_float4(0.f, 0.f, 0.f, 0.f);
    float4 a2 = make_float4(0.f, 0.f, 0.f, 0.f);
    float4 a3 = make_float4(0.f, 0.f, 0.f, 0.f);
    int e = 0;
    for (; e + 4 <= np; e += 4) {
        const int s0 = sidx[e + 0], s1 = sidx[e + 1];
        const int s2 = sidx[e + 2], s3 = sidx[e + 3];
        const float4 v0 = xT[(size_t)s0 * (Bsz / 4) + t];
        const float4 v1 = xT[(size_t)s1 * (Bsz / 4) + t];
        const float4 v2 = xT[(size_t)s2 * (Bsz / 4) + t];
        const float4 v3 = xT[(size_t)s3 * (Bsz / 4) + t];
        a0.x += v0.x; a0.y += v0.y; a0.z += v0.z; a0.w += v0.w;
        a1.x += v1.x; a1.y += v1.y; a1.z += v1.z; a1.w += v1.w;
        a2.x += v2.x; a2.y += v2.y; a2.z += v2.z; a2.w += v2.w;
        a3.x += v3.x; a3.y += v3.y; a3.z += v3.z; a3.w += v3.w;
    }
    for (; e < np; ++e) {
        const float4 v = xT[(size_t)sidx[e] * (Bsz / 4) + t];
        a0.x += v.x; a0.y += v.y; a0.z += v.z; a0.w += v.w;
    }
    for (int ee = MAXIDX; ee < n; ++ee) {   // overflow fallback (never in practice)
        const float4 v = xT[(size_t)csr[beg + ee] * (Bsz / 4) + t];
        a0.x += v.x; a0.y += v.y; a0.z += v.z; a0.w += v.w;
    }
    a0.x += a1.x + a2.x + a3.x;
    a0.y += a1.y + a2.y + a3.y;
    a0.z += a1.z + a2.z + a3.z;
    a0.w += a1.w + a2.w + a3.w;

    const float inv = 1.0f / fmaxf((float)n, 1.0f);
    const float sc = (pnext ? pnext[j] : 1.0f) * inv;
    float4 r;
    r.x = fmaxf(a0.x, 0.f) * sc;
    r.y = fmaxf(a0.y, 0.f) * sc;
    r.z = fmaxf(a0.z, 0.f) * sc;
    r.w = fmaxf(a0.w, 0.f) * sc;
    yT[(size_t)j * (Bsz / 4) + t] = r;
}

// ---------------------------------------------------------------------------
// Head: out (B,10) = y2 (B,256) @ W.T (256,10) + b, with y2 stored transposed.
__global__ __launch_bounds__(256) void head_gemm(
    const float* __restrict__ y2T, const float* __restrict__ W,
    const float* __restrict__ bias, float* __restrict__ out)
{
    __shared__ float ws[10 * 256];
    __shared__ float bs[10];
    const int t = threadIdx.x;
    for (int i = t; i < 10 * 256; i += 256) ws[i] = W[i];
    if (t < 10) bs[t] = bias[t];
    __syncthreads();

    const int b = blockIdx.x * 256 + t;
    float acc[10];
#pragma unroll
    for (int o = 0; o < 10; ++o) acc[o] = bs[o];
    for (int k = 0; k < 256; ++k) {
        const float v = y2T[(size_t)k * Bsz + b];
#pragma unroll
        for (int o = 0; o < 10; ++o) acc[o] += v * ws[o * 256 + k];
    }
#pragma unroll
    for (int o = 0; o < 10; ++o) out[(size_t)b * 10 + o] = acc[o];
}

// ---------------------------------------------------------------------------
extern "C" void kernel_launch(void* const* d_in, const int* in_sizes, int n_in,
                              void* d_out, int out_size, void* d_ws, size_t ws_size,
                              hipStream_t stream)
{
    const float* data = (const float*)d_in[0];
    const float* p0   = (const float*)d_in[1];
    const float* p1   = (const float*)d_in[2];
    const float* p2   = (const float*)d_in[3];
    const float* W    = (const float*)d_in[4];
    const float* bias = (const float*)d_in[5];
    const int* src0 = (const int*)d_in[6];
    const int* dst0 = (const int*)d_in[7];
    const int* src1 = (const int*)d_in[8];
    const int* dst1 = (const int*)d_in[9];
    const int* src2 = (const int*)d_in[10];
    const int* dst2 = (const int*)d_in[11];

    char* ws = (char*)d_ws;
    auto align = [](size_t x) { return (x + 255) & ~size_t(255); };
    size_t o = 0;
    float* dataT = (float*)(ws + o); o = align(o + (size_t)F0 * Bsz * 4);
    float* y0    = (float*)(ws + o); o = align(o + (size_t)NOUT0 * Bsz * 4);
    float* y1    = (float*)(ws + o); o = align(o + (size_t)NOUT1 * Bsz * 4);
    float* y2    = (float*)(ws + o); o = align(o + (size_t)NOUT2 * Bsz * 4);
    int* cnt     = (int*)(ws + o);   o = align(o + (size_t)CNT_N * 4);
    int* offs    = (int*)(ws + o);   o = align(o + (size_t)OFFS_N * 4);
    int* cursor  = (int*)(ws + o);   o = align(o + (size_t)CNT_N * 4);
    int* csr     = (int*)(ws + o);   o = align(o + (size_t)CSR_N * 4);

    hipMemsetAsync(cnt, 0, (size_t)CNT_N * 4, stream);

    constexpr int totE = NE0 + NE1 + NE2;
    count_edges<<<(totE + 255) / 256, 256, 0, stream>>>(dst0, dst1, dst2, cnt);
    scan_offs<<<3, 1024, 0, stream>>>(cnt, offs, cursor);
    scatter_edges<<<(totE + 255) / 256, 256, 0, stream>>>(
        src0, dst0, src1, dst1, src2, dst2, cursor, csr);

    transpose_scale<<<dim3((F0 + 63) / 64, Bsz / 64), 256, 0, stream>>>(data, p0, dataT);

    layer_fwd<<<NOUT0, 256, 0, stream>>>((const float4*)dataT, csr, offs, p1, (float4*)y0);
    layer_fwd<<<NOUT1, 256, 0, stream>>>((const float4*)y0, csr + NE0, offs + NOUT0 + 1, p2, (float4*)y1);
    layer_fwd<<<NOUT2, 256, 0, stream>>>((const float4*)y1, csr + NE0 + NE1, offs + NOUT0 + NOUT1 + 2,
                                          nullptr, (float4*)y2);

    head_gemm<<<Bsz / 256, 256, 0, stream>>>(y2, W, bias, (float*)d_out);
}